// Round 6
// baseline (279.610 us; speedup 1.0000x reference)
//
#include <hip/hip_runtime.h>

#define EPS 1e-10f

// Problem shape (fixed by setup_inputs): [B, C, F, T] = [32, 2, 257, 2000]
constexpr int B  = 32;
constexpr int CF = 514;   // C*F = 2*257
constexpr int T  = 2000;

// ---------------------------------------------------------------------------
// Kernel 1: frame_mean[b][t] = mean_{cf} x[b][cf][t]   (proven rounds 2-4)
// block = (64 t-lanes, 8 cf-groups); coalesced 256B/wave reads; LDS reduce.
// Side effect we exploit in K2: x (131.6 MB) is L3-resident afterwards.
// ---------------------------------------------------------------------------
__global__ __launch_bounds__(512) void k_frame_mean(const float* __restrict__ x,
                                                    float* __restrict__ fm) {
    __shared__ float lds[8][64];
    const int t  = blockIdx.x * 64 + threadIdx.x;   // T=2000 < 32*64=2048
    const int b  = blockIdx.y;
    const int ty = threadIdx.y;

    float s = 0.0f;
    if (t < T) {
        const float* p = x + ((size_t)b * CF + ty) * T + t;
        #pragma unroll 4
        for (int cf = ty; cf < CF; cf += 8) {
            s += *p;
            p += 8 * (size_t)T;
        }
    }
    lds[ty][threadIdx.x] = s;
    __syncthreads();
    if (ty == 0 && t < T) {
        float tot = lds[0][threadIdx.x];
        #pragma unroll
        for (int k = 1; k < 8; ++k) tot += lds[k][threadIdx.x];
        fm[(size_t)b * T + t] = tot / (float)CF;   // IEEE, matches jnp.mean
    }
}

// ---------------------------------------------------------------------------
// Kernel 2: fused scan + normalize. NO grid sync needed: every block
// recomputes the affine EMA scan for its batch in-block (wave 0 only,
// ~700 cy VALU + 8 KB fm row from L2/L3 — trivially redundant across the
// 32 blocks per batch, and bitwise-identical since the instruction sequence
// is deterministic). Wave 0 deposits the block's 64-wide mu window in LDS;
// then all 4 waves stream the normalize over the block's [b, :, t0..t0+64)
// panel. x reads hit L3 (read by K1, <256 MB); kernel is write-bound.
// Round-5 lesson encoded here: no cooperative launch at the occupancy edge.
// ---------------------------------------------------------------------------
__global__ __launch_bounds__(256) void k_scan_norm(const float* __restrict__ x,
                                                   const float* __restrict__ fm,
                                                   const int* __restrict__ d_sl,
                                                   float* __restrict__ out) {
    __shared__ float mu_win[64];
    const int tx  = threadIdx.x & 63;   // t-lane
    const int ty  = threadIdx.x >> 6;   // wave id / cf-group, 0..3
    const int bid = blockIdx.x;         // 0..1023
    const int b   = bid >> 5;
    const int t0  = (bid & 31) * 64;

    if (ty == 0) {
        // ---- affine parallel scan over the whole batch row (round-4 code) ----
        const int lane = tx;
        const int sl   = d_sl[0];
        const float alpha = (float)((double)(sl - 1) / (double)(sl + 1));
        const float* __restrict__ m = fm + (size_t)b * T;
        const int ts = lane * 32;        // lanes 0..61 full, 62 partial, 63 empty

        float v[32];
        if (ts + 32 <= T) {
            #pragma unroll
            for (int j = 0; j < 8; ++j)
                *(float4*)(v + 4 * j) = *(const float4*)(m + ts + 4 * j);
        } else {
            #pragma unroll
            for (int j = 0; j < 32; ++j)
                v[j] = (ts + j < T) ? m[ts + j] : 0.0f;
        }

        // Compose chunk into affine (A, Bv): mu_out = A*mu_in + Bv.
        float A = 1.0f, Bv = 0.0f;
        #pragma unroll
        for (int i = 0; i < 32; ++i) {
            const int tt = ts + i;
            const float ft = (float)tt;
            const float a  = (tt < T) ? fminf((ft - 1.0f) / (ft + 1.0f), alpha) : 1.0f;
            const float vv = (tt < T) ? v[i] : 0.0f;
            Bv = a * Bv + (1.0f - a) * vv;
            A  = a * A;
        }

        // Inclusive wave scan of affine pairs (later ∘ earlier).
        float pA = A, pB = Bv;
        #pragma unroll
        for (int d = 1; d < 64; d <<= 1) {
            const float uA = __shfl_up(pA, d);
            const float uB = __shfl_up(pB, d);
            if (lane >= d) {
                pB = pA * uB + pB;
                pA = pA * uA;
            }
        }

        // Incoming mu = exclusive prefix applied to mu0=0 -> B_excl.
        const float eB = __shfl_up(pB, 1);
        float muv = (lane == 0) ? 0.0f : eB;

        // Serial recompute; keep only this block's 64-wide window (in LDS).
        #pragma unroll
        for (int i = 0; i < 32; ++i) {
            const int tt = ts + i;
            if (tt < T) {
                const float ft = (float)tt;
                const float a  = fminf((ft - 1.0f) / (ft + 1.0f), alpha);
                muv = a * muv + (1.0f - a) * v[i];
                if (tt >= t0 && tt < t0 + 64) mu_win[tt - t0] = muv;
            }
        }
    }
    __syncthreads();

    // ---- normalize the block's panel: out = x / (mu + EPS) ----
    const int t = t0 + tx;
    if (t < T) {
        const float d = mu_win[tx] + EPS;
        const float* p = x + ((size_t)b * CF + ty) * T + t;
        float* q = out + ((size_t)b * CF + ty) * T + t;
        #pragma unroll 4
        for (int cf = ty; cf < CF; cf += 4) {
            *q = *p / d;                 // IEEE div, matches reference
            p += 4 * (size_t)T;
            q += 4 * (size_t)T;
        }
    }
}

// ---------------------------------------------------------------------------
extern "C" void kernel_launch(void* const* d_in, const int* in_sizes, int n_in,
                              void* d_out, int out_size, void* d_ws, size_t ws_size,
                              hipStream_t stream) {
    const float* x    = (const float*)d_in[0];
    const int*   d_sl = (const int*)d_in[1];
    float*       out  = (float*)d_out;

    // workspace: fm [B*T] floats (256 KB)
    float* fm = (float*)d_ws;

    // Kernel 1: per-frame mean
    {
        dim3 grid((T + 63) / 64, B);
        dim3 block(64, 8);
        k_frame_mean<<<grid, block, 0, stream>>>(x, fm);
    }
    // Kernel 2: fused per-block scan + normalize
    {
        k_scan_norm<<<dim3(1024), dim3(256), 0, stream>>>(x, fm, d_sl, out);
    }
}

// Round 8
// 256.573 us; speedup vs baseline: 1.0898x; 1.0898x over previous
//
#include <hip/hip_runtime.h>

#define EPS 1e-10f

// Problem shape (fixed by setup_inputs): [B, C, F, T] = [32, 2, 257, 2000]
constexpr int B  = 32;
constexpr int CF = 514;   // C*F = 2*257
constexpr int T  = 2000;
constexpr int T4 = T / 4; // 500 float4 per row

typedef float f4_native __attribute__((ext_vector_type(4)));

// ---------------------------------------------------------------------------
// Kernel 1: frame_mean[b][t] = mean_{cf} x[b][cf][t]   (proven rounds 2-4)
// block = (64 t-lanes, 8 cf-groups); coalesced 256B/wave reads; LDS reduce.
// Side effect k_norm exploits: x (131.6 MB) is L3-resident afterwards.
// ---------------------------------------------------------------------------
__global__ __launch_bounds__(512) void k_frame_mean(const float* __restrict__ x,
                                                    float* __restrict__ fm) {
    __shared__ float lds[8][64];
    const int t  = blockIdx.x * 64 + threadIdx.x;   // T=2000 < 32*64=2048
    const int b  = blockIdx.y;
    const int ty = threadIdx.y;

    float s = 0.0f;
    if (t < T) {
        const float* p = x + ((size_t)b * CF + ty) * T + t;
        #pragma unroll 4
        for (int cf = ty; cf < CF; cf += 8) {
            s += *p;
            p += 8 * (size_t)T;
        }
    }
    lds[ty][threadIdx.x] = s;
    __syncthreads();
    if (ty == 0 && t < T) {
        float tot = lds[0][threadIdx.x];
        #pragma unroll
        for (int k = 1; k < 8; ++k) tot += lds[k][threadIdx.x];
        fm[(size_t)b * T + t] = tot / (float)CF;   // IEEE, matches jnp.mean
    }
}

// ---------------------------------------------------------------------------
// Kernel 2: parallel affine EMA scan (proven round 4, ~4 us). One wave per
// batch; lane l owns t in [32l, 32l+32). Exact per-t a = min((t-1)/(t+1), α).
// ---------------------------------------------------------------------------
__global__ __launch_bounds__(256) void k_scan_par(const float* __restrict__ fm,
                                                  const int* __restrict__ d_sl,
                                                  float* __restrict__ mu_out) {
    const int wave = threadIdx.x >> 6;           // 0..3
    const int lane = threadIdx.x & 63;
    const int b    = blockIdx.x * 4 + wave;      // grid 8 -> b in [0,32)
    if (b >= B) return;

    const int sl = d_sl[0];
    const float alpha = (float)((double)(sl - 1) / (double)(sl + 1));

    const float* __restrict__ m = fm + (size_t)b * T;
    float* __restrict__ o = mu_out + (size_t)b * T;

    const int t0 = lane * 32;                    // lanes 0..61 full, 62 partial, 63 empty

    float v[32];
    if (t0 + 32 <= T) {
        #pragma unroll
        for (int j = 0; j < 8; ++j)
            *(float4*)(v + 4 * j) = *(const float4*)(m + t0 + 4 * j);
    } else {
        #pragma unroll
        for (int j = 0; j < 32; ++j)
            v[j] = (t0 + j < T) ? m[t0 + j] : 0.0f;
    }

    // Compose chunk into affine (A, Bv): mu_out = A*mu_in + Bv.
    float A = 1.0f, Bv = 0.0f;
    #pragma unroll
    for (int i = 0; i < 32; ++i) {
        const int t = t0 + i;
        const float ft = (float)t;
        const float a  = (t < T) ? fminf((ft - 1.0f) / (ft + 1.0f), alpha) : 1.0f;
        const float vv = (t < T) ? v[i] : 0.0f;
        Bv = a * Bv + (1.0f - a) * vv;
        A  = a * A;
    }

    // Inclusive wave scan of affine pairs (later ∘ earlier).
    float pA = A, pB = Bv;
    #pragma unroll
    for (int d = 1; d < 64; d <<= 1) {
        const float uA = __shfl_up(pA, d);
        const float uB = __shfl_up(pB, d);
        if (lane >= d) {
            pB = pA * uB + pB;
            pA = pA * uA;
        }
    }

    // Incoming mu = exclusive prefix applied to mu0=0 -> B_excl.
    const float eB = __shfl_up(pB, 1);
    float mu = (lane == 0) ? 0.0f : eB;

    // Serial recompute with true incoming mu; store.
    #pragma unroll
    for (int i = 0; i < 32; ++i) {
        const int t = t0 + i;
        if (t < T) {
            const float ft = (float)t;
            const float a  = fminf((ft - 1.0f) / (ft + 1.0f), alpha);
            mu = a * mu + (1.0f - a) * v[i];
            o[t] = mu;
        }
    }
}

// ---------------------------------------------------------------------------
// Kernel 3: out = x / (mu + EPS). Round-2 streaming shape (one float4 per
// thread, 32896 tiny blocks -> ~128 blocks/CU pipelined = massive TLP; the
// round-6 panel-walk version was latency-bound at 34% HBM).
// NT stores via native clang vector type (HIP_vector_type rejected by the
// builtin — round-7 compile fix): out writes don't allocate in L3, so the
// x re-read (L3-resident from K1) stays a hit; kernel is write-bound.
// ---------------------------------------------------------------------------
__global__ __launch_bounds__(256) void k_norm(const float4* __restrict__ x,
                                              const float* __restrict__ mu,
                                              f4_native* __restrict__ out) {
    const int t4  = blockIdx.x * 256 + threadIdx.x;
    if (t4 >= T4) return;
    const int row = blockIdx.y;       // b*CF + cf
    const int b   = row / CF;

    const size_t idx = (size_t)row * T4 + t4;
    const float4 v  = x[idx];
    const float4 m4 = *(const float4*)(mu + (size_t)b * T + (size_t)t4 * 4);

    f4_native r;
    r.x = v.x / (m4.x + EPS);
    r.y = v.y / (m4.y + EPS);
    r.z = v.z / (m4.z + EPS);
    r.w = v.w / (m4.w + EPS);
    __builtin_nontemporal_store(r, &out[idx]);
}

// ---------------------------------------------------------------------------
extern "C" void kernel_launch(void* const* d_in, const int* in_sizes, int n_in,
                              void* d_out, int out_size, void* d_ws, size_t ws_size,
                              hipStream_t stream) {
    const float* x    = (const float*)d_in[0];
    const int*   d_sl = (const int*)d_in[1];
    float*       out  = (float*)d_out;

    // workspace layout: fm [B*T] floats, mu [B*T] floats  (512 KB total)
    float* fm = (float*)d_ws;
    float* mu = fm + (size_t)B * T;

    // Kernel 1: per-frame mean
    {
        dim3 grid((T + 63) / 64, B);
        dim3 block(64, 8);
        k_frame_mean<<<grid, block, 0, stream>>>(x, fm);
    }
    // Kernel 2: parallel EMA scan
    {
        k_scan_par<<<8, 256, 0, stream>>>(fm, d_sl, mu);
    }
    // Kernel 3: normalize (NT stores)
    {
        dim3 grid((T4 + 255) / 256, B * CF);
        dim3 block(256);
        k_norm<<<grid, block, 0, stream>>>((const float4*)x, mu, (f4_native*)out);
    }
}